// Round 5
// baseline (751.336 us; speedup 1.0000x reference)
//
#include <hip/hip_runtime.h>
#include <hip/hip_fp16.h>
#include <cstdio>
#include <cstdint>

#define NREL 16
#define NBASE 8
// bucket = 64 consecutive dst nodes. Record packing: src[16:0] | et[20:17] |
// dlow[26:21]  (requires N <= 2^17 = 131072; N = 100000 here).

// ---------------------------------------------------------------------------
// DPP-based partial-row add (VALU pipe, not LDS): x += dpp_shifted(x).
// ---------------------------------------------------------------------------
template <int CTRL>
__device__ __forceinline__ float dpp_add_f(float x) {
    int xi = __builtin_bit_cast(int, x);
    int yi = __builtin_amdgcn_update_dpp(0, xi, CTRL, 0xF, 0xF, true);
    return x + __builtin_bit_cast(float, yi);
}

// ---------------------------------------------------------------------------
// k_fused1: three independent jobs, selected by block range:
//   [0, nb_pre)            node_pre: hA1(fp16)=h@A_w[0:32], hA2=h@A_w[32:64],
//                                    curr=h@slw            (8 nodes/block)
//   [nb_pre, +nb_hist)     hist:     deg[dst[e]] += 1
//   [nb_pre+nb_hist, +64)  prep:     rel_w = w_comp@weight; relA
// ---------------------------------------------------------------------------
__global__ __launch_bounds__(256) void k_fused1(
        const float* __restrict__ h, const float* __restrict__ A_w,
        const float* __restrict__ slw,
        const float* __restrict__ weight, const float* __restrict__ w_comp,
        const float* __restrict__ attn_emb, const float* __restrict__ A_b,
        const int* __restrict__ dst,
        __half* __restrict__ hA1, float* __restrict__ hA2, float* __restrict__ curr,
        float* __restrict__ rel_w, float* __restrict__ relA, int* __restrict__ deg,
        int N, int E, int nb_pre, int nb_hist) {
    __shared__ __align__(16) float Wall[32 * 128];   // [i][c]: c<32 A1, <64 A2, <96 slw
    __shared__ float hbuf[8 * 33];
    int bx = blockIdx.x;
    int t = threadIdx.x;
    if (bx < nb_pre) {
        // ---- node_pre ----
        #pragma unroll
        for (int k = 0; k < 16; ++k) {
            int idx = t + 256 * k;
            int i = idx >> 7, c = idx & 127;
            float v = 0.f;
            if (c < 32)       v = A_w[i * 32 + c];
            else if (c < 64)  v = A_w[(32 + i) * 32 + (c - 32)];
            else if (c < 96)  v = slw[i * 32 + (c - 64)];
            Wall[idx] = v;
        }
        int n0 = bx * 8;
        {
            int row = t >> 5, col = t & 31;
            int n = n0 + row;
            hbuf[row * 33 + col] = (n < N) ? h[n * 32 + col] : 0.f;
        }
        __syncthreads();
        int nl = t >> 5;
        int c4 = (t & 31) * 4;
        float4 acc = {0.f, 0.f, 0.f, 0.f};
        #pragma unroll 8
        for (int i = 0; i < 32; ++i) {
            float hv = hbuf[nl * 33 + i];
            float4 w = *(const float4*)&Wall[i * 128 + c4];
            acc.x += hv * w.x; acc.y += hv * w.y; acc.z += hv * w.z; acc.w += hv * w.w;
        }
        int n = n0 + nl;
        if (n < N) {
            if (c4 < 32) {
                *(__half2*)&hA1[n * 32 + c4]     = __floats2half2_rn(acc.x, acc.y);
                *(__half2*)&hA1[n * 32 + c4 + 2] = __floats2half2_rn(acc.z, acc.w);
            } else if (c4 < 64) {
                *(float4*)&hA2[n * 32 + (c4 - 32)] = acc;
            } else if (c4 < 96) {
                *(float4*)&curr[n * 32 + (c4 - 64)] = acc;
            }
        }
    } else if (bx < nb_pre + nb_hist) {
        // ---- hist ----
        int e = (bx - nb_pre) * 256 + t;
        if (e < E) atomicAdd(&deg[dst[e]], 1);
    } else {
        // ---- prep ----
        int idx = (bx - nb_pre - nb_hist) * 256 + t;     // 0..16383
        int r = idx >> 10, io = idx & 1023;
        float acc = 0.f;
        #pragma unroll
        for (int b = 0; b < NBASE; ++b)
            acc += w_comp[r * NBASE + b] * weight[b * 1024 + io];
        rel_w[idx] = acc;
        if (idx < NREL * 32) {
            int rr = idx >> 5, o = idx & 31;
            float a = A_b[o];
            #pragma unroll 8
            for (int i = 0; i < 32; ++i)
                a += attn_emb[rr * 32 + i] * A_w[(64 + i) * 32 + o];
            relA[idx] = a;
        }
    }
}

// ---------------------------------------------------------------------------
// k_bsum: per-bucket degree sums (64 nodes per bucket = one 64-lane wave) +
// scale_s partial (sum of log(deg+1)).
// ---------------------------------------------------------------------------
__global__ __launch_bounds__(256) void k_bsum(const int* __restrict__ deg,
        int* __restrict__ bbase, float* __restrict__ scale_s, int N, int nbuck) {
    __shared__ float sf[4];
    int t = threadIdx.x;
    int n = blockIdx.x * 256 + t;
    int wave = t >> 6, lane = t & 63;
    int v = (n < N) ? deg[n] : 0;
    float f = (n < N) ? logf((float)v + 1.f) : 0.f;
    #pragma unroll
    for (int off = 32; off > 0; off >>= 1) {
        v += __shfl_xor(v, off, 64);
        f += __shfl_xor(f, off, 64);
    }
    int bk = blockIdx.x * 4 + wave;
    if (lane == 0) {
        if (bk < nbuck) bbase[bk] = v;
        sf[wave] = f;
    }
    __syncthreads();
    if (t == 0) atomicAdd(scale_s, sf[0] + sf[1] + sf[2] + sf[3]);
}

// ---------------------------------------------------------------------------
// k_bscan: single block exclusive-scans bbase in place (chunked), then
// bbase[nbuck] = total (= E).
// ---------------------------------------------------------------------------
__global__ __launch_bounds__(1024) void k_bscan(int* __restrict__ bbase, int nbuck) {
    __shared__ int sd[1024];
    __shared__ int carry;
    int t = threadIdx.x;
    if (t == 0) carry = 0;
    __syncthreads();
    for (int base = 0; base < nbuck; base += 1024) {
        int v = (base + t < nbuck) ? bbase[base + t] : 0;
        sd[t] = v;
        __syncthreads();
        for (int off = 1; off < 1024; off <<= 1) {
            int x = (t >= off) ? sd[t - off] : 0;
            __syncthreads();
            sd[t] += x;
            __syncthreads();
        }
        int c = carry;
        if (base + t < nbuck) bbase[base + t] = sd[t] - v + c;
        int tot = sd[1023];
        __syncthreads();
        if (t == 0) carry = c + tot;
        __syncthreads();
    }
    if (t == 0) bbase[nbuck] = carry;
}

// ---------------------------------------------------------------------------
// k_fused2: two independent jobs by block range:
//   [0, nb_hrel)         hrel16[n][r*32+o] = fp16( sum_i h[n][i]*rel_w[r][i][o] )
//   [nb_hrel, +nb_scat)  binned append-scatter: edges land in their dst-bucket's
//                        contiguous region (dense writes, no line amplification);
//                        order within a bucket is arbitrary.
// ---------------------------------------------------------------------------
__global__ __launch_bounds__(256) void k_fused2(
        const float* __restrict__ h, const float* __restrict__ rel_w,
        __half* __restrict__ hrel16,
        const int* __restrict__ src, const int* __restrict__ dst,
        const int* __restrict__ et,
        const int* __restrict__ bbase, int* __restrict__ bcur,
        int* __restrict__ packed,
        int N, int E, int nb_hrel) {
    __shared__ float hbuf[32 * 33];
    int bx = blockIdx.x;
    int t = threadIdx.x;
    if (bx < nb_hrel) {
        // ---- hrel (fp16 out) ----
        int n0 = bx * 32;
        #pragma unroll
        for (int k = 0; k < 4; ++k) {
            int idx = t + 256 * k;
            int row = idx >> 5, col = idx & 31;
            int n = n0 + row;
            hbuf[row * 33 + col] = (n < N) ? h[n * 32 + col] : 0.f;
        }
        __syncthreads();
        int w = t >> 6;
        int lane = t & 63;
        const float4* Wg = (const float4*)rel_w;
        int base_f4 = (lane >> 3) * 256 + (lane & 7);
        float4 a0[8], a1[8];
        #pragma unroll
        for (int j = 0; j < 8; ++j) {
            a0[j] = make_float4(0.f, 0.f, 0.f, 0.f);
            a1[j] = make_float4(0.f, 0.f, 0.f, 0.f);
        }
        int brow = w * 8;
        #pragma unroll 4
        for (int i = 0; i < 32; ++i) {
            float4 w0 = Wg[base_f4 + i * 8];
            float4 w1 = Wg[base_f4 + i * 8 + 2048];
            #pragma unroll
            for (int j = 0; j < 8; ++j) {
                float hv = hbuf[(brow + j) * 33 + i];
                a0[j].x += hv * w0.x; a0[j].y += hv * w0.y; a0[j].z += hv * w0.z; a0[j].w += hv * w0.w;
                a1[j].x += hv * w1.x; a1[j].y += hv * w1.y; a1[j].z += hv * w1.z; a1[j].w += hv * w1.w;
            }
        }
        #pragma unroll
        for (int j = 0; j < 8; ++j) {
            int n = n0 + brow + j;
            if (n < N) {
                size_t b0 = (size_t)n * 512 + lane * 4;
                *(__half2*)&hrel16[b0]       = __floats2half2_rn(a0[j].x, a0[j].y);
                *(__half2*)&hrel16[b0 + 2]   = __floats2half2_rn(a0[j].z, a0[j].w);
                *(__half2*)&hrel16[b0 + 256] = __floats2half2_rn(a1[j].x, a1[j].y);
                *(__half2*)&hrel16[b0 + 258] = __floats2half2_rn(a1[j].z, a1[j].w);
            }
        }
    } else {
        // ---- binned append scatter ----
        int e = (bx - nb_hrel) * 256 + t;
        if (e < E) {
            int d = dst[e];
            int bk = d >> 6;
            int pos = bbase[bk] + atomicAdd(&bcur[bk], 1);
            packed[pos] = src[e] | (et[e] << 17) | ((d & 63) << 21);
        }
    }
}

// ---------------------------------------------------------------------------
// k_node_agg: one block per 64-node bucket. Stages hA2 + relA in LDS, streams
// the bucket's (unsorted) records: attention via DPP reduce, a*msg accumulated
// with LDS atomicAdd into lds_agg[64][32]. Fused epilogue, coalesced output.
// ---------------------------------------------------------------------------
__global__ __launch_bounds__(256) void k_node_agg(
        const __half* __restrict__ hrel16, const __half* __restrict__ hA1,
        const float* __restrict__ hA2, const float* __restrict__ relA,
        const float* __restrict__ B_w, const float* __restrict__ B_b,
        const float* __restrict__ curr, const float* __restrict__ bias,
        const int* __restrict__ deg, const int* __restrict__ bbase,
        const int* __restrict__ packed, const float* __restrict__ scale_s,
        float* __restrict__ out, int N) {
    __shared__ float lds_agg[64 * 32];      // 8KB accumulator
    __shared__ float lds_hA2[64 * 32];      // 8KB staged hA2 rows
    __shared__ float lds_relA[NREL * 32];   // 2KB
    int t = threadIdx.x;
    int b = blockIdx.x;
    int n0 = b * 64;
    #pragma unroll
    for (int k = 0; k < 8; ++k) {
        int idx = t + 256 * k;
        lds_agg[idx] = 0.f;
        int n = n0 + (idx >> 5);
        lds_hA2[idx] = (n < N) ? hA2[n * 32 + (idx & 31)] : 0.f;
    }
    #pragma unroll
    for (int k = 0; k < 2; ++k) lds_relA[t + 256 * k] = relA[t + 256 * k];
    __syncthreads();

    int base = bbase[b], end = bbase[b + 1];
    int wave = t >> 6, t64 = t & 63, half = t64 >> 5, o = t64 & 31;
    float bwo = B_w[o], bb = B_b[0];

    for (int c0 = base + wave * 64; c0 < end; c0 += 256) {
        int j = c0 + t64;
        int pk = (j < end) ? packed[j] : 0;
        int m = end - c0; if (m > 64) m = 64;
        for (int k = 0; k < m; k += 2) {
            int idx = k + half;                       // record c0+idx for this half
            int pke = __shfl(pk, idx, 64);
            int s  = pke & 0x1FFFF;
            int r  = (pke >> 17) & 15;
            int dl = (pke >> 21) & 63;
            float msg = __half2float(hrel16[(size_t)s * 512 + (r << 5) + o]);
            float z = __half2float(hA1[(s << 5) + o]) + lds_hA2[(dl << 5) + o]
                    + lds_relA[(r << 5) + o];
            float p = fmaxf(z, 0.f) * bwo;
            // 32-lane sum on VALU pipe: row_shr 1/2/4/8 + row_bcast15
            p = dpp_add_f<0x111>(p);
            p = dpp_add_f<0x112>(p);
            p = dpp_add_f<0x114>(p);
            p = dpp_add_f<0x118>(p);
            p = dpp_add_f<0x142>(p);                  // lane31/63 hold half-sums
            p = __shfl(p, 31, 32) + bb;               // broadcast within each half
            float a = 1.f / (1.f + __expf(-p));
            if (idx < m) atomicAdd(&lds_agg[(dl << 5) + o], a * msg);
        }
    }
    __syncthreads();

    float smean = scale_s[0] / (float)N;
    int oo = t & 31;
    #pragma unroll
    for (int k = 0; k < 8; ++k) {
        int row = (t >> 5) + k * 8;
        int n = n0 + row;
        if (n < N) {
            float dv = (float)deg[n];
            float sc = logf(dv + 1.f);
            float v = curr[n * 32 + oo]
                    + (sc / smean) * lds_agg[row * 32 + oo] / fmaxf(dv, 1.f)
                    + bias[oo];
            out[n * 32 + oo] = fmaxf(v, 0.f);
        }
    }
}

extern "C" void kernel_launch(void* const* d_in, const int* in_sizes, int n_in,
                              void* d_out, int out_size, void* d_ws, size_t ws_size,
                              hipStream_t stream) {
    const float* h        = (const float*)d_in[0];
    const float* weight   = (const float*)d_in[1];
    const float* w_comp   = (const float*)d_in[2];
    const float* slw      = (const float*)d_in[3];
    const float* bias     = (const float*)d_in[4];
    const float* attn_emb = (const float*)d_in[5];
    const float* A_w      = (const float*)d_in[6];
    const float* A_b      = (const float*)d_in[7];
    const float* B_w      = (const float*)d_in[8];
    const float* B_b      = (const float*)d_in[9];
    const int*   src      = (const int*)d_in[10];
    const int*   dst      = (const int*)d_in[11];
    const int*   et       = (const int*)d_in[12];
    float*       out      = (float*)d_out;

    int N = in_sizes[0] / 32;
    int E = in_sizes[10];
    int nbuck = (N + 63) >> 6;

    char* ws = (char*)d_ws;
    size_t off = 0;
    auto alloc = [&](size_t nbytes) {
        char* p = ws + off;
        off += (nbytes + 63) & ~((size_t)63);
        return p;
    };
    int*    deg     = (int*)   alloc((size_t)N * 4);
    int*    bcur    = (int*)   alloc((size_t)nbuck * 4);
    float*  scale_s = (float*) alloc(4);
    size_t zero_bytes = off;                       // deg + bcur + scale_s
    int*    bbase   = (int*)   alloc((size_t)(nbuck + 1) * 4);
    float*  rel_w   = (float*) alloc((size_t)NREL * 1024 * 4);
    float*  relA    = (float*) alloc((size_t)NREL * 32 * 4);
    __half* hA1     = (__half*)alloc((size_t)N * 32 * 2);
    float*  hA2     = (float*) alloc((size_t)N * 32 * 4);
    float*  curr    = (float*) alloc((size_t)N * 32 * 4);
    int*    packed  = (int*)   alloc((size_t)E * 4);
    __half* hrel16  = (__half*)alloc((size_t)N * 512 * 2);
    size_t need = off;

    if (ws_size < need) {
        fprintf(stderr, "kernel_launch: ws too small (%zu < %zu bytes) — no work launched\n",
                ws_size, need);
        return;
    }

    (void)hipMemsetAsync(d_ws, 0, zero_bytes, stream);

    int nb_pre  = (N + 7) / 8;
    int nb_hist = (E + 255) / 256;
    int nb_prep = 64;
    k_fused1<<<nb_pre + nb_hist + nb_prep, 256, 0, stream>>>(
        h, A_w, slw, weight, w_comp, attn_emb, A_b, dst,
        hA1, hA2, curr, rel_w, relA, deg, N, E, nb_pre, nb_hist);

    k_bsum<<<(N + 255) / 256, 256, 0, stream>>>(deg, bbase, scale_s, N, nbuck);
    k_bscan<<<1, 1024, 0, stream>>>(bbase, nbuck);

    int nb_hrel = (N + 31) / 32;
    int nb_scat = (E + 255) / 256;
    k_fused2<<<nb_hrel + nb_scat, 256, 0, stream>>>(
        h, rel_w, hrel16, src, dst, et, bbase, bcur, packed, N, E, nb_hrel);

    k_node_agg<<<nbuck, 256, 0, stream>>>(
        hrel16, hA1, hA2, relA, B_w, B_b, curr, bias,
        deg, bbase, packed, scale_s, out, N);
}

// Round 6
// 539.098 us; speedup vs baseline: 1.3937x; 1.3937x over previous
//
#include <hip/hip_runtime.h>
#include <hip/hip_fp16.h>
#include <cstdio>
#include <cstdint>

#define NREL 16
#define NBASE 8
// bucket = 16 consecutive dst nodes. Record packing:
//   src[16:0] | et[20:17] | dlow[24:21]   (N <= 2^17; N = 100000 here)

// ---------------------------------------------------------------------------
// DPP-based partial-row add (VALU pipe, not LDS): x += dpp_shifted(x).
// ---------------------------------------------------------------------------
template <int CTRL>
__device__ __forceinline__ float dpp_add_f(float x) {
    int xi = __builtin_bit_cast(int, x);
    int yi = __builtin_amdgcn_update_dpp(0, xi, CTRL, 0xF, 0xF, true);
    return x + __builtin_bit_cast(float, yi);
}

// ---------------------------------------------------------------------------
// k_fused1: three independent jobs, selected by block range:
//   [0, nb_pre)            node_pre: hA1(fp16)=h@A_w[0:32], hA2=h@A_w[32:64],
//                                    curr=h@slw            (8 nodes/block)
//   [nb_pre, +nb_hist)     hist:     deg[dst[e]] += 1
//   [nb_pre+nb_hist, +64)  prep:     rel_w = w_comp@weight; relA
// ---------------------------------------------------------------------------
__global__ __launch_bounds__(256) void k_fused1(
        const float* __restrict__ h, const float* __restrict__ A_w,
        const float* __restrict__ slw,
        const float* __restrict__ weight, const float* __restrict__ w_comp,
        const float* __restrict__ attn_emb, const float* __restrict__ A_b,
        const int* __restrict__ dst,
        __half* __restrict__ hA1, float* __restrict__ hA2, float* __restrict__ curr,
        float* __restrict__ rel_w, float* __restrict__ relA, int* __restrict__ deg,
        int N, int E, int nb_pre, int nb_hist) {
    __shared__ __align__(16) float Wall[32 * 128];   // [i][c]: c<32 A1, <64 A2, <96 slw
    __shared__ float hbuf[8 * 33];
    int bx = blockIdx.x;
    int t = threadIdx.x;
    if (bx < nb_pre) {
        // ---- node_pre ----
        #pragma unroll
        for (int k = 0; k < 16; ++k) {
            int idx = t + 256 * k;
            int i = idx >> 7, c = idx & 127;
            float v = 0.f;
            if (c < 32)       v = A_w[i * 32 + c];
            else if (c < 64)  v = A_w[(32 + i) * 32 + (c - 32)];
            else if (c < 96)  v = slw[i * 32 + (c - 64)];
            Wall[idx] = v;
        }
        int n0 = bx * 8;
        {
            int row = t >> 5, col = t & 31;
            int n = n0 + row;
            hbuf[row * 33 + col] = (n < N) ? h[n * 32 + col] : 0.f;
        }
        __syncthreads();
        int nl = t >> 5;
        int c4 = (t & 31) * 4;
        float4 acc = {0.f, 0.f, 0.f, 0.f};
        #pragma unroll 8
        for (int i = 0; i < 32; ++i) {
            float hv = hbuf[nl * 33 + i];
            float4 w = *(const float4*)&Wall[i * 128 + c4];
            acc.x += hv * w.x; acc.y += hv * w.y; acc.z += hv * w.z; acc.w += hv * w.w;
        }
        int n = n0 + nl;
        if (n < N) {
            if (c4 < 32) {
                *(__half2*)&hA1[n * 32 + c4]     = __floats2half2_rn(acc.x, acc.y);
                *(__half2*)&hA1[n * 32 + c4 + 2] = __floats2half2_rn(acc.z, acc.w);
            } else if (c4 < 64) {
                *(float4*)&hA2[n * 32 + (c4 - 32)] = acc;
            } else if (c4 < 96) {
                *(float4*)&curr[n * 32 + (c4 - 64)] = acc;
            }
        }
    } else if (bx < nb_pre + nb_hist) {
        // ---- hist ----
        int e = (bx - nb_pre) * 256 + t;
        if (e < E) atomicAdd(&deg[dst[e]], 1);
    } else {
        // ---- prep ----
        int idx = (bx - nb_pre - nb_hist) * 256 + t;     // 0..16383
        int r = idx >> 10, io = idx & 1023;
        float acc = 0.f;
        #pragma unroll
        for (int b = 0; b < NBASE; ++b)
            acc += w_comp[r * NBASE + b] * weight[b * 1024 + io];
        rel_w[idx] = acc;
        if (idx < NREL * 32) {
            int rr = idx >> 5, o = idx & 31;
            float a = A_b[o];
            #pragma unroll 8
            for (int i = 0; i < 32; ++i)
                a += attn_emb[rr * 32 + i] * A_w[(64 + i) * 32 + o];
            relA[idx] = a;
        }
    }
}

// ---------------------------------------------------------------------------
// k_bsum: per-bucket (16 nodes) degree sums + scale_s partial sums.
// ---------------------------------------------------------------------------
__global__ __launch_bounds__(256) void k_bsum(const int* __restrict__ deg,
        int* __restrict__ bbase, float* __restrict__ scale_s, int N, int nbuck) {
    __shared__ float sf[4];
    int t = threadIdx.x;
    int n = blockIdx.x * 256 + t;
    int v = (n < N) ? deg[n] : 0;
    float f = (n < N) ? logf((float)v + 1.f) : 0.f;
    int vv = v;
    #pragma unroll
    for (int off = 8; off > 0; off >>= 1) vv += __shfl_xor(vv, off, 16);
    #pragma unroll
    for (int off = 32; off > 0; off >>= 1) f += __shfl_xor(f, off, 64);
    int wave = t >> 6, lane = t & 63;
    if ((t & 15) == 0) {
        int bk = (blockIdx.x * 256 + t) >> 4;
        if (bk < nbuck) bbase[bk] = vv;
    }
    if (lane == 0) sf[wave] = f;
    __syncthreads();
    if (t == 0) atomicAdd(scale_s, sf[0] + sf[1] + sf[2] + sf[3]);
}

// ---------------------------------------------------------------------------
// k_bscan: single block exclusive-scans bbase in place (chunked), then
// bbase[nbuck] = total (= E).
// ---------------------------------------------------------------------------
__global__ __launch_bounds__(1024) void k_bscan(int* __restrict__ bbase, int nbuck) {
    __shared__ int sd[1024];
    __shared__ int carry;
    int t = threadIdx.x;
    if (t == 0) carry = 0;
    __syncthreads();
    for (int base = 0; base < nbuck; base += 1024) {
        int v = (base + t < nbuck) ? bbase[base + t] : 0;
        sd[t] = v;
        __syncthreads();
        for (int off = 1; off < 1024; off <<= 1) {
            int x = (t >= off) ? sd[t - off] : 0;
            __syncthreads();
            sd[t] += x;
            __syncthreads();
        }
        int c = carry;
        if (base + t < nbuck) bbase[base + t] = sd[t] - v + c;
        int tot = sd[1023];
        __syncthreads();
        if (t == 0) carry = c + tot;
        __syncthreads();
    }
    if (t == 0) bbase[nbuck] = carry;
}

// ---------------------------------------------------------------------------
// k_fused2: two independent jobs by block range:
//   [0, nb_hrel)         hrel16[n][r*32+o] = fp16( sum_i h[n][i]*rel_w[r][i][o] )
//   [nb_hrel, +nb_scat)  binned append-scatter into 16-node dst buckets.
// ---------------------------------------------------------------------------
__global__ __launch_bounds__(256) void k_fused2(
        const float* __restrict__ h, const float* __restrict__ rel_w,
        __half* __restrict__ hrel16,
        const int* __restrict__ src, const int* __restrict__ dst,
        const int* __restrict__ et,
        const int* __restrict__ bbase, int* __restrict__ bcur,
        int* __restrict__ packed,
        int N, int E, int nb_hrel) {
    __shared__ float hbuf[32 * 33];
    int bx = blockIdx.x;
    int t = threadIdx.x;
    if (bx < nb_hrel) {
        // ---- hrel (fp16 out) ----
        int n0 = bx * 32;
        #pragma unroll
        for (int k = 0; k < 4; ++k) {
            int idx = t + 256 * k;
            int row = idx >> 5, col = idx & 31;
            int n = n0 + row;
            hbuf[row * 33 + col] = (n < N) ? h[n * 32 + col] : 0.f;
        }
        __syncthreads();
        int w = t >> 6;
        int lane = t & 63;
        const float4* Wg = (const float4*)rel_w;
        int base_f4 = (lane >> 3) * 256 + (lane & 7);
        float4 a0[8], a1[8];
        #pragma unroll
        for (int j = 0; j < 8; ++j) {
            a0[j] = make_float4(0.f, 0.f, 0.f, 0.f);
            a1[j] = make_float4(0.f, 0.f, 0.f, 0.f);
        }
        int brow = w * 8;
        #pragma unroll 4
        for (int i = 0; i < 32; ++i) {
            float4 w0 = Wg[base_f4 + i * 8];
            float4 w1 = Wg[base_f4 + i * 8 + 2048];
            #pragma unroll
            for (int j = 0; j < 8; ++j) {
                float hv = hbuf[(brow + j) * 33 + i];
                a0[j].x += hv * w0.x; a0[j].y += hv * w0.y; a0[j].z += hv * w0.z; a0[j].w += hv * w0.w;
                a1[j].x += hv * w1.x; a1[j].y += hv * w1.y; a1[j].z += hv * w1.z; a1[j].w += hv * w1.w;
            }
        }
        #pragma unroll
        for (int j = 0; j < 8; ++j) {
            int n = n0 + brow + j;
            if (n < N) {
                size_t b0 = (size_t)n * 512 + lane * 4;
                *(__half2*)&hrel16[b0]       = __floats2half2_rn(a0[j].x, a0[j].y);
                *(__half2*)&hrel16[b0 + 2]   = __floats2half2_rn(a0[j].z, a0[j].w);
                *(__half2*)&hrel16[b0 + 256] = __floats2half2_rn(a1[j].x, a1[j].y);
                *(__half2*)&hrel16[b0 + 258] = __floats2half2_rn(a1[j].z, a1[j].w);
            }
        }
    } else {
        // ---- binned append scatter (dense writes within bucket regions) ----
        int e = (bx - nb_hrel) * 256 + t;
        if (e < E) {
            int d = dst[e];
            int bk = d >> 4;
            int pos = bbase[bk] + atomicAdd(&bcur[bk], 1);
            packed[pos] = src[e] | (et[e] << 17) | ((d & 15) << 21);
        }
    }
}

// ---------------------------------------------------------------------------
// k_node_agg: one block per 16-node bucket (grid = N/16 = 6250). Stages
// hA2/relA in LDS; streams the bucket's (unsorted) records with 4-deep
// batching: issue 8 records' gathers, then run 8 independent DPP/sigmoid
// chains; accumulate a*msg via LDS atomics. Fused epilogue.
// ---------------------------------------------------------------------------
__global__ __launch_bounds__(256) void k_node_agg(
        const __half* __restrict__ hrel16, const __half* __restrict__ hA1,
        const float* __restrict__ hA2, const float* __restrict__ relA,
        const float* __restrict__ B_w, const float* __restrict__ B_b,
        const float* __restrict__ curr, const float* __restrict__ bias,
        const int* __restrict__ deg, const int* __restrict__ bbase,
        const int* __restrict__ packed, const float* __restrict__ scale_s,
        float* __restrict__ out, int N) {
    __shared__ float lds_agg[16 * 32];      // 2KB accumulator
    __shared__ float lds_hA2[16 * 32];      // 2KB staged hA2 rows
    __shared__ float lds_relA[NREL * 32];   // 2KB
    int t = threadIdx.x;
    int b = blockIdx.x;
    int n0 = b * 16;
    {
        int idx0 = t, idx1 = t + 256;
        lds_agg[idx0 & 511] = 0.f;          // t covers 0..255; second half below
        lds_agg[(idx1) & 511] = 0.f;
        int n = n0 + (idx0 >> 5);
        lds_hA2[idx0] = (n < N) ? hA2[n * 32 + (idx0 & 31)] : 0.f;
        n = n0 + (idx1 >> 5);
        lds_hA2[idx1] = (n < N) ? hA2[n * 32 + (idx1 & 31)] : 0.f;
        lds_relA[idx0] = relA[idx0];
        lds_relA[idx1] = relA[idx1];
    }
    __syncthreads();

    int base = bbase[b], end = bbase[b + 1];
    int wave = t >> 6, t64 = t & 63, half = t64 >> 5, o = t64 & 31;
    float bwo = B_w[o], bb = B_b[0];

    for (int c0 = base + wave * 64; c0 < end; c0 += 256) {
        int j = c0 + t64;
        int pk = (j < end) ? packed[j] : 0;
        int m = end - c0; if (m > 64) m = 64;
        for (int k = 0; k < m; k += 8) {
            float msg[4], za[4];
            int   dl[4];
            bool  val[4];
            #pragma unroll
            for (int jj = 0; jj < 4; ++jj) {
                int idx = k + 2 * jj + half;
                val[jj] = (idx < m);
                int pv = __shfl(pk, idx, 64);
                pv = val[jj] ? pv : 0;
                int s = pv & 0x1FFFF;
                int r = (pv >> 17) & 15;
                dl[jj] = (pv >> 21) & 15;
                msg[jj] = __half2float(hrel16[(size_t)s * 512 + (r << 5) + o]);
                za[jj]  = __half2float(hA1[(s << 5) + o]) + lds_relA[(r << 5) + o];
            }
            #pragma unroll
            for (int jj = 0; jj < 4; ++jj) {
                float z = za[jj] + lds_hA2[(dl[jj] << 5) + o];
                float p = fmaxf(z, 0.f) * bwo;
                p = dpp_add_f<0x111>(p);
                p = dpp_add_f<0x112>(p);
                p = dpp_add_f<0x114>(p);
                p = dpp_add_f<0x118>(p);
                p = dpp_add_f<0x142>(p);          // lane31/63 hold half-sums
                p = __shfl(p, 31, 32) + bb;       // broadcast within each half
                float a = 1.f / (1.f + __expf(-p));
                if (val[jj]) atomicAdd(&lds_agg[(dl[jj] << 5) + o], a * msg[jj]);
            }
        }
    }
    __syncthreads();

    float smean = scale_s[0] / (float)N;
    #pragma unroll
    for (int k = 0; k < 2; ++k) {
        int idx = t + 256 * k;                    // 0..511
        int row = idx >> 5, oo = idx & 31;
        int n = n0 + row;
        if (n < N) {
            float dv = (float)deg[n];
            float sc = logf(dv + 1.f);
            float v = curr[n * 32 + oo]
                    + (sc / smean) * lds_agg[idx] / fmaxf(dv, 1.f)
                    + bias[oo];
            out[n * 32 + oo] = fmaxf(v, 0.f);
        }
    }
}

extern "C" void kernel_launch(void* const* d_in, const int* in_sizes, int n_in,
                              void* d_out, int out_size, void* d_ws, size_t ws_size,
                              hipStream_t stream) {
    const float* h        = (const float*)d_in[0];
    const float* weight   = (const float*)d_in[1];
    const float* w_comp   = (const float*)d_in[2];
    const float* slw      = (const float*)d_in[3];
    const float* bias     = (const float*)d_in[4];
    const float* attn_emb = (const float*)d_in[5];
    const float* A_w      = (const float*)d_in[6];
    const float* A_b      = (const float*)d_in[7];
    const float* B_w      = (const float*)d_in[8];
    const float* B_b      = (const float*)d_in[9];
    const int*   src      = (const int*)d_in[10];
    const int*   dst      = (const int*)d_in[11];
    const int*   et       = (const int*)d_in[12];
    float*       out      = (float*)d_out;

    int N = in_sizes[0] / 32;
    int E = in_sizes[10];
    int nbuck = (N + 15) >> 4;

    char* ws = (char*)d_ws;
    size_t off = 0;
    auto alloc = [&](size_t nbytes) {
        char* p = ws + off;
        off += (nbytes + 63) & ~((size_t)63);
        return p;
    };
    int*    deg     = (int*)   alloc((size_t)N * 4);
    int*    bcur    = (int*)   alloc((size_t)nbuck * 4);
    float*  scale_s = (float*) alloc(4);
    size_t zero_bytes = off;                       // deg + bcur + scale_s
    int*    bbase   = (int*)   alloc((size_t)(nbuck + 1) * 4);
    float*  rel_w   = (float*) alloc((size_t)NREL * 1024 * 4);
    float*  relA    = (float*) alloc((size_t)NREL * 32 * 4);
    __half* hA1     = (__half*)alloc((size_t)N * 32 * 2);
    float*  hA2     = (float*) alloc((size_t)N * 32 * 4);
    float*  curr    = (float*) alloc((size_t)N * 32 * 4);
    int*    packed  = (int*)   alloc((size_t)E * 4);
    __half* hrel16  = (__half*)alloc((size_t)N * 512 * 2);
    size_t need = off;

    if (ws_size < need) {
        fprintf(stderr, "kernel_launch: ws too small (%zu < %zu bytes) — no work launched\n",
                ws_size, need);
        return;
    }

    (void)hipMemsetAsync(d_ws, 0, zero_bytes, stream);

    int nb_pre  = (N + 7) / 8;
    int nb_hist = (E + 255) / 256;
    int nb_prep = 64;
    k_fused1<<<nb_pre + nb_hist + nb_prep, 256, 0, stream>>>(
        h, A_w, slw, weight, w_comp, attn_emb, A_b, dst,
        hA1, hA2, curr, rel_w, relA, deg, N, E, nb_pre, nb_hist);

    k_bsum<<<(N + 255) / 256, 256, 0, stream>>>(deg, bbase, scale_s, N, nbuck);
    k_bscan<<<1, 1024, 0, stream>>>(bbase, nbuck);

    int nb_hrel = (N + 31) / 32;
    int nb_scat = (E + 255) / 256;
    k_fused2<<<nb_hrel + nb_scat, 256, 0, stream>>>(
        h, rel_w, hrel16, src, dst, et, bbase, bcur, packed, N, E, nb_hrel);

    k_node_agg<<<nbuck, 256, 0, stream>>>(
        hrel16, hA1, hA2, relA, B_w, B_b, curr, bias,
        deg, bbase, packed, scale_s, out, N);
}